// Round 8
// baseline (234.163 us; speedup 1.0000x reference)
//
#include <hip/hip_runtime.h>

#define B  16
#define N  256
#define F  128
#define NB 32
#define INF_F 1000000000.0f

__device__ __forceinline__ float xf(float v, int gi, int gk) {
    // where(adj>0, adj, INF) then diag=0 (diag wins), exactly like reference
    return (gi == gk) ? 0.0f : ((v > 0.0f) ? v : INF_F);
}
__device__ __forceinline__ float4 ld4(const float* p) { return *(const float4*)p; }
__device__ __forceinline__ float4 min4(float4 a, float4 b) {
    return make_float4(fminf(a.x, b.x), fminf(a.y, b.y),
                       fminf(a.z, b.z), fminf(a.w, b.w));
}

// ---------------------------------------------------------------------------
// min-plus squaring, K-split x4 ACROSS BLOCKS (round-5 proven structure).
// Block (b,bi,bj,ks): 256 threads / 4 waves, output tile 128x64, k-chunk 64
// (ks*64..), staged as two 32-k tiles, double-buffered. 8x4 acc per lane.
// Source S is the COMBINED matrix (or adj on FIRST, with xf in COMMIT).
// Writes partial ks to Out + ks*M. A stored [row][k ^ ((row>>3&7)<<2)]
// (XOR-quad swizzle, involution on write AND read). B [k][64] linear.
// grid 512 -> 2 blocks/CU -> 8 waves/CU -> 2 waves/SIMD.
// min reassociation bit-exact; adds identical operand pairs as reference.
// ---------------------------------------------------------------------------
template<bool FIRST>
__global__ __launch_bounds__(256, 2) void k_minplus(const float* __restrict__ S,
                                                    float* __restrict__ Out) {
    int blk = blockIdx.x;            // ((b*2+bi)*4+bj)*4+ks, 512 total
    int ks = blk & 3;
    int bj = (blk >> 2) & 3;
    int bi = (blk >> 4) & 1;
    int b  = blk >> 5;
    const int bofs = b * N * N;
    const int kc = ks * 64;          // k-chunk base
    const int ri = bi * 128;         // tile row base
    const int cj = bj * 64;          // tile col base

    __shared__ __align__(16) float As[2][128 * 32];
    __shared__ __align__(16) float Bs[2][32 * 64];

    int tid = threadIdx.x;
    int ty = tid >> 4, tx = tid & 15;

    float4 ra[4], rb[2];             // staging registers

    // ---- issue global loads for k-tile kt (A: 4 quads/lane, B: 2 quads/lane)
#define LOADS(kt) {                                                            \
        int kbase = kc + (kt) * 32;                                            \
        _Pragma("unroll")                                                      \
        for (int u = 0; u < 4; ++u) {                                          \
            int lin4 = u * 256 + tid;                                          \
            int arow = lin4 >> 3, aqc = (lin4 & 7) << 2;                       \
            ra[u] = ld4(S + bofs + (ri + arow) * N + kbase + aqc);             \
        }                                                                      \
        _Pragma("unroll")                                                      \
        for (int u = 0; u < 2; ++u) {                                          \
            int lin4 = u * 256 + tid;                                          \
            int brow = lin4 >> 4, bqc = (lin4 & 15) << 2;                      \
            rb[u] = ld4(S + bofs + (kbase + brow) * N + cj + bqc);             \
        }                                                                      \
    }

    // ---- commit staged registers to LDS buffer bufi (xform only on FIRST)
#define COMMIT(kt, bufi) {                                                     \
        int kbase = kc + (kt) * 32;                                            \
        _Pragma("unroll")                                                      \
        for (int u = 0; u < 4; ++u) {                                          \
            int lin4 = u * 256 + tid;                                          \
            int arow = lin4 >> 3, aqc = (lin4 & 7) << 2;                       \
            float4 v = ra[u];                                                  \
            if (FIRST) {                                                       \
                int gi = ri + arow, gk = kbase + aqc;                          \
                v.x = xf(v.x, gi, gk);     v.y = xf(v.y, gi, gk + 1);          \
                v.z = xf(v.z, gi, gk + 2); v.w = xf(v.w, gi, gk + 3);          \
            }                                                                  \
            *(float4*)&As[bufi][arow * 32 + (aqc ^ (((arow >> 3) & 7) << 2))] = v; \
        }                                                                      \
        _Pragma("unroll")                                                      \
        for (int u = 0; u < 2; ++u) {                                          \
            int lin4 = u * 256 + tid;                                          \
            int brow = lin4 >> 4, bqc = (lin4 & 15) << 2;                      \
            float4 v = rb[u];                                                  \
            if (FIRST) {                                                       \
                int gk = kbase + brow, gj = cj + bqc;                          \
                v.x = xf(v.x, gk, gj);     v.y = xf(v.y, gk, gj + 1);          \
                v.z = xf(v.z, gk, gj + 2); v.w = xf(v.w, gk, gj + 3);          \
            }                                                                  \
            *(float4*)&Bs[bufi][brow * 64 + bqc] = v;                          \
        }                                                                      \
    }

    float acc[8][4];
#pragma unroll
    for (int r = 0; r < 8; ++r)
#pragma unroll
        for (int c = 0; c < 4; ++c) acc[r][c] = 3.0e38f;

    const int aswz = (ty & 7) << 2;  // == ((row>>3)&7)<<2 for rows ty*8..ty*8+7

#define KSTEP(comp, i) {                                                       \
        float4 q = Bq[i];                                                      \
        _Pragma("unroll")                                                      \
        for (int rr = 0; rr < 8; ++rr) {                                       \
            acc[rr][0] = fminf(acc[rr][0], Aq[rr].comp + q.x);                 \
            acc[rr][1] = fminf(acc[rr][1], Aq[rr].comp + q.y);                 \
            acc[rr][2] = fminf(acc[rr][2], Aq[rr].comp + q.z);                 \
            acc[rr][3] = fminf(acc[rr][3], Aq[rr].comp + q.w);                 \
        } }

#define COMPUTE(bufi) {                                                        \
        _Pragma("unroll")                                                      \
        for (int kq = 0; kq < 8; ++kq) {                                       \
            int k0 = kq * 4;                                                   \
            float4 Aq[8];                                                      \
            _Pragma("unroll")                                                  \
            for (int rr = 0; rr < 8; ++rr)                                     \
                Aq[rr] = *(const float4*)&As[bufi][(ty * 8 + rr) * 32 + (k0 ^ aswz)]; \
            float4 Bq[4];                                                      \
            _Pragma("unroll")                                                  \
            for (int kk = 0; kk < 4; ++kk)                                     \
                Bq[kk] = *(const float4*)&Bs[bufi][(k0 + kk) * 64 + tx * 4];   \
            KSTEP(x, 0) KSTEP(y, 1) KSTEP(z, 2) KSTEP(w, 3)                    \
        } }

    LOADS(0)
    COMMIT(0, 0)
    __syncthreads();
    LOADS(1)                 // issue early: latency hides under COMPUTE(0)
    COMPUTE(0)
    COMMIT(1, 1)
    __syncthreads();
    COMPUTE(1)

    const size_t M = (size_t)B * N * N;
    float* O = Out + (size_t)ks * M + bofs;
#pragma unroll
    for (int rr = 0; rr < 8; ++rr) {
        int row = ri + ty * 8 + rr;
        *(float4*)&O[row * N + cj + tx * 4] =
            make_float4(acc[rr][0], acc[rr][1], acc[rr][2], acc[rr][3]);
    }
}

// ---------------------------------------------------------------------------
// elementwise 4-way min combine of the partial planes: C = min(P0..P3).
// Pure min reassociation -> bit-exact.
// ---------------------------------------------------------------------------
__global__ __launch_bounds__(256) void k_combine(const float* __restrict__ P,
                                                 float* __restrict__ C) {
    const size_t M = (size_t)B * N * N;
    size_t o = ((size_t)blockIdx.x * 256 + threadIdx.x) * 4;   // over M floats
    float4 v = min4(min4(ld4(P + o),         ld4(P + M + o)),
                    min4(ld4(P + 2 * M + o), ld4(P + 3 * M + o)));
    *(float4*)((float*)C + o) = v;
}

// ---------------------------------------------------------------------------
// per row (b,i): radix-select 32 smallest (value,index) keys from the 4-way
// min of partials; emit indices ascending == sort(stable_argsort(row)[:32]).
// (round-5 proven kernel)
// ---------------------------------------------------------------------------
__global__ __launch_bounds__(256) void k_select(const float* __restrict__ D0,
                                                const float* __restrict__ D1,
                                                const float* __restrict__ D2,
                                                const float* __restrict__ D3,
                                                int* __restrict__ nbr) {
    int row = blockIdx.x;           // b*N + i
    int j = threadIdx.x;
    int lane = j & 63;
    int wid = j >> 6;

    __shared__ int wcnt[4], weq[4], wsel[4];

    int idx = row * N + j;
    float d = fminf(fminf(D0[idx], D1[idx]), fminf(D2[idx], D3[idx]));
    unsigned u = __float_as_uint(d);   // d >= 0 -> monotone bits

    unsigned prefix = 0;
    for (int bb = 31; bb >= 0; --bb) {
        unsigned cand = prefix | (1u << bb);
        unsigned long long m = __ballot(u < cand);
        if (lane == 0) wcnt[wid] = __popcll(m);
        __syncthreads();
        int c = wcnt[0] + wcnt[1] + wcnt[2] + wcnt[3];
        if (c <= 31) prefix = cand;
        __syncthreads();
    }

    unsigned long long mlt = __ballot(u < prefix);
    unsigned long long meq = __ballot(u == prefix);
    if (lane == 0) { wcnt[wid] = __popcll(mlt); weq[wid] = __popcll(meq); }
    __syncthreads();
    int cless = wcnt[0] + wcnt[1] + wcnt[2] + wcnt[3];
    int need = 32 - cless;
    int eqbefore = 0;
    for (int w = 0; w < wid; ++w) eqbefore += weq[w];
    int tie_rank = eqbefore + __popcll(meq & ((1ull << lane) - 1ull));
    bool flag = (u < prefix) || (u == prefix && tie_rank < need);

    unsigned long long msel = __ballot(flag);
    if (lane == 0) wsel[wid] = __popcll(msel);
    __syncthreads();
    int base = 0;
    for (int w = 0; w < wid; ++w) base += wsel[w];
    int pos = base + __popcll(msel & ((1ull << lane) - 1ull));
    if (flag) nbr[row * NB + pos] = j;
}

// ---------------------------------------------------------------------------
// fused gathers: blocks [0,16384) do features, [16384,32768) do adj+edge
// ---------------------------------------------------------------------------
__global__ __launch_bounds__(256) void k_gather(const float* __restrict__ feat,
                                                const float* __restrict__ adj,
                                                const float* __restrict__ ef,
                                                const int* __restrict__ nbr,
                                                float* __restrict__ outF,
                                                float* __restrict__ outA,
                                                float* __restrict__ outE) {
    int bidx = blockIdx.x;
    if (bidx < 16384) {
        int gid = bidx * 256 + threadIdx.x;    // B*N*NB*(F/4)
        int c4  = gid & 31;
        int r   = (gid >> 5) & 31;
        int row = gid >> 10;
        int b   = row >> 8;
        int nj = nbr[row * NB + r];
        float4 v = ld4(&feat[((b << 8) + nj) * F + (c4 << 2)]);
        ((float4*)outF)[gid] = v;
    } else {
        int gid = (bidx - 16384) * 256 + threadIdx.x;   // B*N*NB*NB
        int c   = gid & 31;
        int r   = (gid >> 5) & 31;
        int row = gid >> 10;
        int b   = row >> 8;
        int nr = nbr[row * NB + r];
        int nc = nbr[row * NB + c];
        int base = (b << 16) + (nr << 8) + nc;
        outA[gid] = adj[base];
        float3 e = *(const float3*)&ef[(long)base * 3];
        *(float3*)&outE[(long)gid * 3] = e;
    }
}

// ---------------------------------------------------------------------------
extern "C" void kernel_launch(void* const* d_in, const int* in_sizes, int n_in,
                              void* d_out, int out_size, void* d_ws, size_t ws_size,
                              hipStream_t stream) {
    const float* feat = (const float*)d_in[0];   // (B,N,F)
    const float* adj  = (const float*)d_in[1];   // (B,N,N)
    const float* ef   = (const float*)d_in[2];   // (B,N,N,3)

    float* out  = (float*)d_out;
    float* outF = out;                                   // B*N*NB*F
    float* outA = out + (size_t)B * N * NB * F;          // B*N*NB*NB
    float* outE = outA + (size_t)B * N * NB * NB;        // B*N*NB*NB*3

    const size_t M = (size_t)B * N * N;                  // 1,048,576
    // 4 partial planes (16 MB) live in d_out; dead before gathers overwrite.
    // Combined matrix + nbr in d_ws (4.5 MB, proven placement).
    float* W  = out;
    float* Cb = (float*)d_ws;
    int*  nbr = (int*)(Cb + M);

    // 8 squarings like the reference. Each step: combine partials once
    // (20 MB traffic) then square from the combined source (25 MB staged
    // reads instead of round-5's 100 MB).
    k_minplus<true><<<512, 256, 0, stream>>>(adj, W);
    for (int s = 1; s < 8; ++s) {
        k_combine<<<1024, 256, 0, stream>>>(W, Cb);
        k_minplus<false><<<512, 256, 0, stream>>>(Cb, W);
    }
    // final combine fused into select (round-5 proven 4-pointer version)
    k_select<<<B * N, 256, 0, stream>>>(W, W + M, W + 2 * M, W + 3 * M, nbr);

    k_gather<<<32768, 256, 0, stream>>>(feat, adj, ef, nbr, outF, outA, outE);
}